// Round 9
// baseline (304.632 us; speedup 1.0000x reference)
//
#include <hip/hip_runtime.h>
#include <math.h>

// Problem constants
#define Bsz 2
#define Tsz 2048
#define Csz 768
#define Hsz 12
#define C3  2304      // 3*C
#define WIN 256
#define LN_EPS 1e-5f

// Q pre-scale: D^-0.5 * log2(e), folded into the QKV GEMM epilogue so the
// attention kernel works in the exp2 domain with no per-element multiplies.
#define QSCALE 0.1803368801111137f

typedef short bf16x8 __attribute__((ext_vector_type(8)));  // 8 bf16 (4 VGPRs)
typedef short bf16x4 __attribute__((ext_vector_type(4)));  // 4 bf16 (2 VGPRs)
typedef float f32x4  __attribute__((ext_vector_type(4)));

// fp32 -> bf16 round-to-nearest-even
__device__ __forceinline__ unsigned short f2b(float f) {
    unsigned int u = __float_as_uint(f);
    u = (u + 0x7fffu + ((u >> 16) & 1u)) >> 16;
    return (unsigned short)u;
}
// bf16 bits -> fp32
__device__ __forceinline__ float b2f(unsigned short u) {
    return __uint_as_float(((unsigned int)u) << 16);
}

// ---------------------------------------------------------------------------
// Elementwise fp32 -> bf16 (4 elems/thread)
// ---------------------------------------------------------------------------
__global__ __launch_bounds__(256) void convert_bf16(
    const float* __restrict__ src, unsigned short* __restrict__ dst, int n4)
{
    int idx = blockIdx.x * 256 + threadIdx.x;
    if (idx >= n4) return;
    float4 v = *(const float4*)(src + (size_t)idx * 4);
    unsigned int lo = (unsigned int)f2b(v.x) | ((unsigned int)f2b(v.y) << 16);
    unsigned int hi = (unsigned int)f2b(v.z) | ((unsigned int)f2b(v.w) << 16);
    uint2 o; o.x = lo; o.y = hi;
    *(uint2*)(dst + (size_t)idx * 4) = o;
}

// ---------------------------------------------------------------------------
// fp32 [K][N] -> bf16 [N][K] (transpose + convert)
// ---------------------------------------------------------------------------
__global__ __launch_bounds__(256) void transpose_conv(
    const float* __restrict__ src, unsigned short* __restrict__ dst, int K, int N)
{
    __shared__ float tile[32][33];
    const int n0 = blockIdx.x * 32, k0 = blockIdx.y * 32;
    const int tx = threadIdx.x & 31, ty = threadIdx.x >> 5;   // 32 x 8
    #pragma unroll
    for (int p = 0; p < 4; ++p)
        tile[ty + p * 8][tx] = src[(size_t)(k0 + ty + p * 8) * N + n0 + tx];
    __syncthreads();
    #pragma unroll
    for (int p = 0; p < 4; ++p)
        dst[(size_t)(n0 + ty + p * 8) * K + k0 + tx] = f2b(tile[tx][ty + p * 8]);
}

// ---------------------------------------------------------------------------
// V transpose: qkvb bf16 [B*T][3C] -> VT bf16 [B*H][64][T]
// ---------------------------------------------------------------------------
__global__ __launch_bounds__(256) void transpose_v(
    const unsigned short* __restrict__ qkv, unsigned short* __restrict__ VT)
{
    __shared__ unsigned short tile[32][33];
    const int bh = blockIdx.z;
    const int b = bh / Hsz, h = bh % Hsz;
    const int t0 = blockIdx.x * 32, d0 = blockIdx.y * 32;
    const int tx = threadIdx.x & 31, ty = threadIdx.x >> 5;
    #pragma unroll
    for (int p = 0; p < 4; ++p) {
        int t = t0 + ty + p * 8;
        tile[ty + p * 8][tx] =
            qkv[(size_t)(b * Tsz + t) * C3 + 2 * Csz + h * 64 + d0 + tx];
    }
    __syncthreads();
    #pragma unroll
    for (int p = 0; p < 4; ++p) {
        int d = d0 + ty + p * 8;
        VT[((size_t)bh * 64 + d) * Tsz + t0 + tx] = tile[tx][ty + p * 8];
    }
}

// ---------------------------------------------------------------------------
// fsel[r] = 0.5 + 0.5*sigmoid(mamba_scale * dot(LN(mamba_raw[r]), sel_w) + sel_b)
// ---------------------------------------------------------------------------
__global__ __launch_bounds__(256) void sel_kernel(
    const float* __restrict__ mr, const float* __restrict__ ln_w,
    const float* __restrict__ ln_b, const float* __restrict__ scale_p,
    const float* __restrict__ sel_w, const float* __restrict__ sel_b,
    float* __restrict__ sel)
{
    __shared__ float red1[256];
    __shared__ float red2[256];
    __shared__ float mu_sh, rstd_sh;

    const int r = blockIdx.x;
    const int tid = threadIdx.x;
    const float* row = mr + (size_t)r * Csz;

    float s = 0.f, s2 = 0.f;
    for (int c = tid; c < Csz; c += 256) {
        float x = row[c];
        s += x; s2 += x * x;
    }
    red1[tid] = s; red2[tid] = s2;
    __syncthreads();
    for (int st = 128; st > 0; st >>= 1) {
        if (tid < st) { red1[tid] += red1[tid + st]; red2[tid] += red2[tid + st]; }
        __syncthreads();
    }
    if (tid == 0) {
        float mu = red1[0] * (1.f / Csz);
        float var = red2[0] * (1.f / Csz) - mu * mu;
        mu_sh = mu;
        rstd_sh = rsqrtf(var + LN_EPS);
    }
    __syncthreads();
    const float mu = mu_sh, rstd = rstd_sh;

    float dot = 0.f;
    for (int c = tid; c < Csz; c += 256) {
        float xn = (row[c] - mu) * rstd * ln_w[c] + ln_b[c];
        dot += xn * sel_w[c];
    }
    red1[tid] = dot;
    __syncthreads();
    for (int st = 128; st > 0; st >>= 1) {
        if (tid < st) red1[tid] += red1[tid + st];
        __syncthreads();
    }
    if (tid == 0) {
        float z = scale_p[0] * red1[0] + sel_b[0];
        sel[r] = 0.5f + 0.5f / (1.f + __expf(-z));
    }
}

// ---------------------------------------------------------------------------
// bf16 MFMA GEMM, B^T input: C[M,N] = A[M,K] @ BT[N,K]^T + bias
// cols < scale_cols additionally scaled by QSCALE (folds attention q-scale).
// ---------------------------------------------------------------------------
template<int OUT_BF16>
__global__ __launch_bounds__(256) void gemm_bt_mfma(
    const unsigned short* __restrict__ A, const unsigned short* __restrict__ BT,
    const float* __restrict__ bias, void* __restrict__ Cout,
    int M, int N, int K, int scale_cols)
{
    __shared__ unsigned short As[128 * 32];
    __shared__ unsigned short Bs[128 * 32];

    const int tid = threadIdx.x;
    const int lane = tid & 63, widx = tid >> 6;
    const int lm = lane & 15, quad = lane >> 4;
    const int wm = widx >> 1, wn = widx & 1;
    const int m0 = blockIdx.y * 128, n0 = blockIdx.x * 128;

    f32x4 acc[4][4];
    #pragma unroll
    for (int mt = 0; mt < 4; ++mt)
        #pragma unroll
        for (int nt = 0; nt < 4; ++nt)
            acc[mt][nt] = f32x4{0.f, 0.f, 0.f, 0.f};

    int rowS[2], cS[2];
    #pragma unroll
    for (int t = 0; t < 2; ++t) {
        int idx = t * 256 + tid;
        rowS[t] = idx >> 2;
        cS[t] = idx & 3;
    }

    bf16x8 pa[2], pb[2];
    #pragma unroll
    for (int t = 0; t < 2; ++t) {
        pa[t] = *(const bf16x8*)(A + (size_t)(m0 + rowS[t]) * K + cS[t] * 8);
        pb[t] = *(const bf16x8*)(BT + (size_t)(n0 + rowS[t]) * K + cS[t] * 8);
    }

    const int nk = K / 32;
    for (int kt = 0; kt < nk; ++kt) {
        __syncthreads();
        #pragma unroll
        for (int t = 0; t < 2; ++t) {
            *(bf16x8*)(&As[rowS[t] * 32 + ((cS[t] ^ ((rowS[t] >> 1) & 3)) << 3)]) = pa[t];
            *(bf16x8*)(&Bs[rowS[t] * 32 + ((cS[t] ^ ((rowS[t] >> 1) & 3)) << 3)]) = pb[t];
        }
        __syncthreads();
        if (kt + 1 < nk) {
            int k0 = (kt + 1) * 32;
            #pragma unroll
            for (int t = 0; t < 2; ++t) {
                pa[t] = *(const bf16x8*)(A + (size_t)(m0 + rowS[t]) * K + k0 + cS[t] * 8);
                pb[t] = *(const bf16x8*)(BT + (size_t)(n0 + rowS[t]) * K + k0 + cS[t] * 8);
            }
        }
        bf16x8 af[4], bf[4];
        #pragma unroll
        for (int mt = 0; mt < 4; ++mt) {
            int m = wm * 64 + mt * 16 + lm;
            af[mt] = *(const bf16x8*)(&As[m * 32 + ((quad ^ ((m >> 1) & 3)) << 3)]);
        }
        #pragma unroll
        for (int nt = 0; nt < 4; ++nt) {
            int n = wn * 64 + nt * 16 + lm;
            bf[nt] = *(const bf16x8*)(&Bs[n * 32 + ((quad ^ ((n >> 1) & 3)) << 3)]);
        }
        #pragma unroll
        for (int mt = 0; mt < 4; ++mt)
            #pragma unroll
            for (int nt = 0; nt < 4; ++nt)
                acc[mt][nt] = __builtin_amdgcn_mfma_f32_16x16x32_bf16(
                    af[mt], bf[nt], acc[mt][nt], 0, 0, 0);
    }

    float bv[4], scl[4];
    #pragma unroll
    for (int nt = 0; nt < 4; ++nt) {
        bv[nt] = bias[n0 + wn * 64 + nt * 16 + lm];
        scl[nt] = ((n0 + wn * 64 + nt * 16) < scale_cols) ? QSCALE : 1.0f;
    }

    #pragma unroll
    for (int mt = 0; mt < 4; ++mt) {
        #pragma unroll
        for (int nt = 0; nt < 4; ++nt) {
            int col = n0 + wn * 64 + nt * 16 + lm;
            #pragma unroll
            for (int r = 0; r < 4; ++r) {
                int row = m0 + wm * 64 + mt * 16 + quad * 4 + r;
                float v = (acc[mt][nt][r] + bv[nt]) * scl[nt];
                if (OUT_BF16)
                    ((unsigned short*)Cout)[(size_t)row * N + col] = f2b(v);
                else
                    ((float*)Cout)[(size_t)row * N + col] = v;
            }
        }
    }
}

// ---------------------------------------------------------------------------
// MFMA flash attention, dual softmax, no-max (R8-validated), S^T variant:
// S^T = mfma(A=K-frag, B=Q-frag) -- same registers as R8, swapped operands.
// S^T C-layout (key=quad*4+r, query=lm) IS the B-operand layout of
// mfma_f32_16x16x16_bf16, so P^T feeds PV directly from registers:
// O^T = mfma(A=V^T-frag, B=P^T). NO LDS in the K-loop (Pbuf deleted).
// l = per-lane register sum of dequantized P (exact match with PV operand)
// + 2 cross-quad shuffles per tile. K prefetched one tile ahead; V rolling.
// Merge: R7/R8 2-slot addition tree re-indexed to O^T (rows=d, cols=query).
// LDS: Mrg[2][2][65][17] floats = 17680 B.
// ---------------------------------------------------------------------------
__global__ __launch_bounds__(256) void attn_mfma(
    const unsigned short* __restrict__ qkv, const unsigned short* __restrict__ VT,
    const float* __restrict__ fsel_arr, const float* __restrict__ lw_p,
    const float* __restrict__ gw_p, unsigned short* __restrict__ attnb)
{
    // Mrg[slot][branch][row 0..63 = d (O^T), row 64 = l][col = query lm]
    __shared__ float Mrg[2][2][65][17];                    // 17680 B

    const int tid = threadIdx.x;
    const int widx = tid >> 6, lane = tid & 63;
    const int lm = lane & 15, quad = lane >> 4;

    const int strip = 127 - (int)(blockIdx.x / 24);   // heavy strips first
    const int bh = (int)(blockIdx.x % 24);
    const int h = bh % Hsz, b = bh / Hsz;
    const int i0 = strip * 16;

    const unsigned short* qkv_b = qkv + (size_t)b * Tsz * C3;

    // Q fragment (B operand for S^T): lane holds Q[i0+lm][d = quad*8 + j]
    const unsigned short* qrow = qkv_b + (size_t)(i0 + lm) * C3 + h * 64 + quad * 8;
    const bf16x8 qf0 = *(const bf16x8*)qrow;
    const bf16x8 qf1 = *(const bf16x8*)(qrow + 32);

    const int qi = i0 + lm;                         // this lane's query row

    float l_g = 0.f, l_l = 0.f;
    f32x4 Og[4], Ol[4];                             // O^T: [dt] x (r -> d=dt*16+quad*4+r)
    #pragma unroll
    for (int dt = 0; dt < 4; ++dt) {
        Og[dt] = f32x4{0.f, 0.f, 0.f, 0.f};
        Ol[dt] = f32x4{0.f, 0.f, 0.f, 0.f};
    }

    const int jtd = i0 >> 6;                        // diagonal 64-tile
    const int jtl = (jtd - 4) > 0 ? (jtd - 4) : 0;  // first local tile

    // K fragments (A operand): lane holds K[j0+nt*16+lm][d = quad*8 + j]
    bf16x8 kf[4][2];
    {
        const int j0p = widx * 64;
        if (widx <= jtd) {
            const unsigned short* kb =
                qkv_b + (size_t)(j0p + lm) * C3 + Csz + h * 64 + quad * 8;
            #pragma unroll
            for (int nt = 0; nt < 4; ++nt) {
                kf[nt][0] = *(const bf16x8*)(kb + (size_t)nt * 16 * C3);
                kf[nt][1] = *(const bf16x8*)(kb + (size_t)nt * 16 * C3 + 32);
            }
        }
    }

    for (int jt = widx; jt <= jtd; jt += 4) {
        const int j0 = jt * 64;
        const bool diag = (jt == jtd);
        const bool loc = (jt >= jtl);

        // ---- S^T = K . Q^T (swapped operands; same registers as before) ----
        f32x4 sT[4];
        #pragma unroll
        for (int nt = 0; nt < 4; ++nt) {
            f32x4 z = f32x4{0.f, 0.f, 0.f, 0.f};
            z = __builtin_amdgcn_mfma_f32_16x16x32_bf16(kf[nt][0], qf0, z, 0, 0, 0);
            z = __builtin_amdgcn_mfma_f32_16x16x32_bf16(kf[nt][1], qf1, z, 0, 0, 0);
            sT[nt] = z;
        }

        // ---- prefetch next K tile (registers free after MFMA issue) ----
        if (jt + 4 <= jtd) {
            const unsigned short* kb =
                qkv_b + (size_t)(j0 + 256 + lm) * C3 + Csz + h * 64 + quad * 8;
            #pragma unroll
            for (int nt = 0; nt < 4; ++nt) {
                kf[nt][0] = *(const bf16x8*)(kb + (size_t)nt * 16 * C3);
                kf[nt][1] = *(const bf16x8*)(kb + (size_t)nt * 16 * C3 + 32);
            }
        }

        // ---- V A-frags for dt=0 (rolling prefetch over dt in PV loop) ----
        const unsigned short* vbase =
            VT + ((size_t)bh * 64 + lm) * Tsz + j0 + quad * 4;
        bf16x4 vcur[4], vnext[4];
        #pragma unroll
        for (int nt = 0; nt < 4; ++nt)
            vcur[nt] = *(const bf16x4*)(vbase + nt * 16);

        // ---- fsel (keyed by kj = j0 + nt*16 + quad*4 + r) ----
        float4 fs4[4];
        #pragma unroll
        for (int nt = 0; nt < 4; ++nt)
            fs4[nt] = *(const float4*)(fsel_arr + b * Tsz + j0 + nt * 16 + quad * 4);

        // ---- softmax (no max): P^T = exp2(sT * fs), masked -> 0 ----
        bf16x4 pb_g[4], pb_l[4];
        float lg_part = 0.f, ll_part = 0.f;
        #pragma unroll
        for (int nt = 0; nt < 4; ++nt) {
            const int kj0 = j0 + nt * 16 + quad * 4;
            const float* fsp = (const float*)&fs4[nt];
            #pragma unroll
            for (int r = 0; r < 4; ++r) {
                const int kj = kj0 + r;
                float p = exp2f(sT[nt][r] * fsp[r]);
                p = (diag && (kj > qi)) ? 0.f : p;
                unsigned short us = f2b(p);
                pb_g[nt][r] = (short)us;
                lg_part += b2f(us);
            }
            if (loc) {
                #pragma unroll
                for (int r = 0; r < 4; ++r) {
                    const int kj = kj0 + r;
                    float p = exp2f(sT[nt][r]);
                    p = (kj > qi || kj < qi - WIN) ? 0.f : p;
                    unsigned short us = f2b(p);
                    pb_l[nt][r] = (short)us;
                    ll_part += b2f(us);
                }
            }
        }
        // sum across the 4 quads (lanes lm+16*quad) -> full row sums
        lg_part += __shfl_xor(lg_part, 16);
        lg_part += __shfl_xor(lg_part, 32);
        l_g += lg_part;
        if (loc) {
            ll_part += __shfl_xor(ll_part, 16);
            ll_part += __shfl_xor(ll_part, 32);
            l_l += ll_part;
        }

        // ---- PV: O^T += V^T . P^T  (16x16x16, P^T direct from registers) ----
        #pragma unroll
        for (int dt = 0; dt < 4; ++dt) {
            if (dt < 3) {
                #pragma unroll
                for (int nt = 0; nt < 4; ++nt)
                    vnext[nt] = *(const bf16x4*)(vbase + (size_t)(dt + 1) * 16 * Tsz + nt * 16);
            }
            #pragma unroll
            for (int nt = 0; nt < 4; ++nt) {
                Og[dt] = __builtin_amdgcn_mfma_f32_16x16x16bf16_1k(
                    vcur[nt], pb_g[nt], Og[dt], 0, 0, 0);
                if (loc)
                    Ol[dt] = __builtin_amdgcn_mfma_f32_16x16x16bf16_1k(
                        vcur[nt], pb_l[nt], Ol[dt], 0, 0, 0);
            }
            #pragma unroll
            for (int nt = 0; nt < 4; ++nt) vcur[nt] = vnext[nt];
        }
    }

    // ==== 2-slot pairwise merge tree (pure sums; O^T rows = d) ====
    auto write_slot = [&](int slot) {
        #pragma unroll
        for (int dt = 0; dt < 4; ++dt)
            #pragma unroll
            for (int r = 0; r < 4; ++r) {
                Mrg[slot][0][dt * 16 + quad * 4 + r][lm] = Og[dt][r];
                Mrg[slot][1][dt * 16 + quad * 4 + r][lm] = Ol[dt][r];
            }
        if (quad == 0) {
            Mrg[slot][0][64][lm] = l_g;
            Mrg[slot][1][64][lm] = l_l;
        }
    };
    auto combine_slot = [&](int slot) {
        #pragma unroll
        for (int dt = 0; dt < 4; ++dt)
            #pragma unroll
            for (int r = 0; r < 4; ++r) {
                Og[dt][r] += Mrg[slot][0][dt * 16 + quad * 4 + r][lm];
                Ol[dt][r] += Mrg[slot][1][dt * 16 + quad * 4 + r][lm];
            }
        l_g += Mrg[slot][0][64][lm];
        l_l += Mrg[slot][1][64][lm];
    };

    if (widx == 1) write_slot(0);
    if (widx == 3) write_slot(1);
    __syncthreads();
    if (widx == 0) combine_slot(0);
    if (widx == 2) combine_slot(1);
    __syncthreads();
    if (widx == 2) write_slot(0);
    __syncthreads();

    if (widx == 0) {
        combine_slot(0);      // wave 0 holds the full-strip sums

        float wl = 1.f / (1.f + __expf(-lw_p[0]));
        float wg = 1.f / (1.f + __expf(-gw_p[0]));
        float ws = wl + wg;
        wl /= ws; wg /= ws;

        const float cg = wg / l_g;      // l is per-lane (query = lm)
        const float cl = wl / l_l;

        unsigned short* orow =
            attnb + (size_t)(b * Tsz + i0 + lm) * Csz + h * 64 + quad * 4;
        #pragma unroll
        for (int dt = 0; dt < 4; ++dt) {
            bf16x4 o;
            #pragma unroll
            for (int r = 0; r < 4; ++r)
                o[r] = (short)f2b(Og[dt][r] * cg + Ol[dt][r] * cl);
            *(bf16x4*)(orow + dt * 16) = o;
        }
    }
}

// ---------------------------------------------------------------------------
extern "C" void kernel_launch(void* const* d_in, const int* in_sizes, int n_in,
                              void* d_out, int out_size, void* d_ws, size_t ws_size,
                              hipStream_t stream)
{
    const float* x          = (const float*)d_in[0];
    const float* mamba_raw  = (const float*)d_in[1];
    const float* c_attn_w   = (const float*)d_in[2];
    const float* c_attn_b   = (const float*)d_in[3];
    const float* c_proj_w   = (const float*)d_in[4];
    const float* c_proj_b   = (const float*)d_in[5];
    const float* ln_w       = (const float*)d_in[6];
    const float* ln_b       = (const float*)d_in[7];
    const float* mamba_sc   = (const float*)d_in[8];
    const float* sel_w      = (const float*)d_in[9];
    const float* sel_b      = (const float*)d_in[10];
    const float* local_w    = (const float*)d_in[11];
    const float* global_w   = (const float*)d_in[12];
    float* out = (float*)d_out;

    const int M = Bsz * Tsz;                 // 4096

    // Workspace layout (ushort units)
    unsigned short* xb    = (unsigned short*)d_ws;       // 4096*768
    unsigned short* wq    = xb + (size_t)M * Csz;        // 2304*768 (c_attn_w^T)
    unsigned short* wp    = wq + (size_t)C3 * Csz;       // 768*768  (c_proj_w^T)
    unsigned short* qkvb  = wp + (size_t)Csz * Csz;      // 4096*2304
    unsigned short* vt    = qkvb + (size_t)M * C3;       // 24*64*2048
    unsigned short* attnb = vt + (size_t)Bsz * Hsz * 64 * Tsz; // 4096*768
    float* sel = (float*)(attnb + (size_t)M * Csz);      // 4096

    // 1) conversions
    convert_bf16<<<(M * Csz / 4 + 255) / 256, 256, 0, stream>>>(x, xb, M * Csz / 4);
    {
        dim3 g(C3 / 32, Csz / 32);
        transpose_conv<<<g, 256, 0, stream>>>(c_attn_w, wq, Csz, C3);
    }
    {
        dim3 g(Csz / 32, Csz / 32);
        transpose_conv<<<g, 256, 0, stream>>>(c_proj_w, wp, Csz, Csz);
    }

    // 2) selector (outputs 0.5 + 0.5*sigmoid)
    sel_kernel<<<M, 256, 0, stream>>>(mamba_raw, ln_w, ln_b, mamba_sc,
                                      sel_w, sel_b, sel);

    // 3) QKV projection (bf16 out; Q cols pre-scaled by QSCALE)
    {
        dim3 g(C3 / 128, M / 128);
        gemm_bt_mfma<1><<<g, 256, 0, stream>>>(xb, wq, c_attn_b, qkvb,
                                               M, C3, Csz, Csz);
    }

    // 4) V transpose
    {
        dim3 g(Tsz / 32, 64 / 32, Bsz * Hsz);
        transpose_v<<<g, 256, 0, stream>>>(qkvb, vt);
    }

    // 5) attention (bf16 out): one block per strip per (b,h)
    attn_mfma<<<128 * Hsz * Bsz, 256, 0, stream>>>(qkvb, vt, sel,
                                                   local_w, global_w, attnb);

    // 6) output projection (fp32 out, no scaling)
    {
        dim3 g(Csz / 128, M / 128);
        gemm_bt_mfma<0><<<g, 256, 0, stream>>>(attnb, wp, c_proj_b, out,
                                               M, Csz, Csz, 0);
    }
}

// Round 10
// 274.982 us; speedup vs baseline: 1.1078x; 1.1078x over previous
//
#include <hip/hip_runtime.h>
#include <math.h>

// Problem constants
#define Bsz 2
#define Tsz 2048
#define Csz 768
#define Hsz 12
#define C3  2304      // 3*C
#define WIN 256
#define LN_EPS 1e-5f

// Q pre-scale: D^-0.5 * log2(e), folded into the QKV GEMM epilogue so the
// attention kernel works in the exp2 domain with no per-element multiplies.
#define QSCALE 0.1803368801111137f

typedef short bf16x8 __attribute__((ext_vector_type(8)));  // 8 bf16 (4 VGPRs)
typedef float f32x4  __attribute__((ext_vector_type(4)));

// fp32 -> bf16 round-to-nearest-even
__device__ __forceinline__ unsigned short f2b(float f) {
    unsigned int u = __float_as_uint(f);
    u = (u + 0x7fffu + ((u >> 16) & 1u)) >> 16;
    return (unsigned short)u;
}
// fp32 -> bf16 truncation (1 op; P>=0 and l self-normalizes, bias cancels)
__device__ __forceinline__ unsigned short f2b_trunc(float f) {
    return (unsigned short)(__float_as_uint(f) >> 16);
}

// async global->LDS, 16B per lane; LDS dest is wave-uniform base + lane*16
__device__ __forceinline__ void load_lds16(const unsigned short* g,
                                           unsigned short* l) {
    __builtin_amdgcn_global_load_lds(
        (const __attribute__((address_space(1))) unsigned int*)g,
        (__attribute__((address_space(3))) unsigned int*)l, 16, 0, 0);
}

// ---------------------------------------------------------------------------
// Elementwise fp32 -> bf16 (4 elems/thread)
// ---------------------------------------------------------------------------
__global__ __launch_bounds__(256) void convert_bf16(
    const float* __restrict__ src, unsigned short* __restrict__ dst, int n4)
{
    int idx = blockIdx.x * 256 + threadIdx.x;
    if (idx >= n4) return;
    float4 v = *(const float4*)(src + (size_t)idx * 4);
    unsigned int lo = (unsigned int)f2b(v.x) | ((unsigned int)f2b(v.y) << 16);
    unsigned int hi = (unsigned int)f2b(v.z) | ((unsigned int)f2b(v.w) << 16);
    uint2 o; o.x = lo; o.y = hi;
    *(uint2*)(dst + (size_t)idx * 4) = o;
}

// ---------------------------------------------------------------------------
// fp32 [K][N] -> bf16 [N][K] (transpose + convert)
// ---------------------------------------------------------------------------
__global__ __launch_bounds__(256) void transpose_conv(
    const float* __restrict__ src, unsigned short* __restrict__ dst, int K, int N)
{
    __shared__ float tile[32][33];
    const int n0 = blockIdx.x * 32, k0 = blockIdx.y * 32;
    const int tx = threadIdx.x & 31, ty = threadIdx.x >> 5;   // 32 x 8
    #pragma unroll
    for (int p = 0; p < 4; ++p)
        tile[ty + p * 8][tx] = src[(size_t)(k0 + ty + p * 8) * N + n0 + tx];
    __syncthreads();
    #pragma unroll
    for (int p = 0; p < 4; ++p)
        dst[(size_t)(n0 + ty + p * 8) * K + k0 + tx] = f2b(tile[tx][ty + p * 8]);
}

// ---------------------------------------------------------------------------
// V transpose: qkvb bf16 [B*T][3C] -> VT bf16 [B*H][64][T]
// ---------------------------------------------------------------------------
__global__ __launch_bounds__(256) void transpose_v(
    const unsigned short* __restrict__ qkv, unsigned short* __restrict__ VT)
{
    __shared__ unsigned short tile[32][33];
    const int bh = blockIdx.z;
    const int b = bh / Hsz, h = bh % Hsz;
    const int t0 = blockIdx.x * 32, d0 = blockIdx.y * 32;
    const int tx = threadIdx.x & 31, ty = threadIdx.x >> 5;
    #pragma unroll
    for (int p = 0; p < 4; ++p) {
        int t = t0 + ty + p * 8;
        tile[ty + p * 8][tx] =
            qkv[(size_t)(b * Tsz + t) * C3 + 2 * Csz + h * 64 + d0 + tx];
    }
    __syncthreads();
    #pragma unroll
    for (int p = 0; p < 4; ++p) {
        int d = d0 + ty + p * 8;
        VT[((size_t)bh * 64 + d) * Tsz + t0 + tx] = tile[tx][ty + p * 8];
    }
}

// ---------------------------------------------------------------------------
// fsel[r] = 0.5 + 0.5*sigmoid(mamba_scale * dot(LN(mamba_raw[r]), sel_w) + sel_b)
// ---------------------------------------------------------------------------
__global__ __launch_bounds__(256) void sel_kernel(
    const float* __restrict__ mr, const float* __restrict__ ln_w,
    const float* __restrict__ ln_b, const float* __restrict__ scale_p,
    const float* __restrict__ sel_w, const float* __restrict__ sel_b,
    float* __restrict__ sel)
{
    __shared__ float red1[256];
    __shared__ float red2[256];
    __shared__ float mu_sh, rstd_sh;

    const int r = blockIdx.x;
    const int tid = threadIdx.x;
    const float* row = mr + (size_t)r * Csz;

    float s = 0.f, s2 = 0.f;
    for (int c = tid; c < Csz; c += 256) {
        float x = row[c];
        s += x; s2 += x * x;
    }
    red1[tid] = s; red2[tid] = s2;
    __syncthreads();
    for (int st = 128; st > 0; st >>= 1) {
        if (tid < st) { red1[tid] += red1[tid + st]; red2[tid] += red2[tid + st]; }
        __syncthreads();
    }
    if (tid == 0) {
        float mu = red1[0] * (1.f / Csz);
        float var = red2[0] * (1.f / Csz) - mu * mu;
        mu_sh = mu;
        rstd_sh = rsqrtf(var + LN_EPS);
    }
    __syncthreads();
    const float mu = mu_sh, rstd = rstd_sh;

    float dot = 0.f;
    for (int c = tid; c < Csz; c += 256) {
        float xn = (row[c] - mu) * rstd * ln_w[c] + ln_b[c];
        dot += xn * sel_w[c];
    }
    red1[tid] = dot;
    __syncthreads();
    for (int st = 128; st > 0; st >>= 1) {
        if (tid < st) red1[tid] += red1[tid + st];
        __syncthreads();
    }
    if (tid == 0) {
        float z = scale_p[0] * red1[0] + sel_b[0];
        sel[r] = 0.5f + 0.5f / (1.f + __expf(-z));
    }
}

// ---------------------------------------------------------------------------
// bf16 MFMA GEMM, B^T input: C[M,N] = A[M,K] @ BT[N,K]^T + bias
// R10: staging via global_load_lds width=16 (m97 pattern). The XOR swizzle
// (chunk c stored at c_swz = c ^ ((row>>1)&3)) is realized by permuting the
// per-lane GLOBAL source chunk, since the LDS dest is fixed at lane*16.
// Fragment ds_read_b128s then hit 8 distinct 4-bank groups -> 2-way (free).
// cols < scale_cols additionally scaled by QSCALE (folds attention q-scale).
// ---------------------------------------------------------------------------
template<int OUT_BF16>
__global__ __launch_bounds__(256) void gemm_bt_mfma(
    const unsigned short* __restrict__ A, const unsigned short* __restrict__ BT,
    const float* __restrict__ bias, void* __restrict__ Cout,
    int M, int N, int K, int scale_cols)
{
    __shared__ unsigned short As[128 * 32];
    __shared__ unsigned short Bs[128 * 32];

    const int tid = threadIdx.x;
    const int lane = tid & 63, widx = tid >> 6;
    const int lm = lane & 15, quad = lane >> 4;
    const int wm = widx >> 1, wn = widx & 1;
    const int m0 = blockIdx.y * 128, n0 = blockIdx.x * 128;

    f32x4 acc[4][4];
    #pragma unroll
    for (int mt = 0; mt < 4; ++mt)
        #pragma unroll
        for (int nt = 0; nt < 4; ++nt)
            acc[mt][nt] = f32x4{0.f, 0.f, 0.f, 0.f};

    // staging plan: instr t in {0,1}: row = widx*32 + t*16 + lane/4,
    // LDS dest = (widx*32 + t*16)*32 + lane*8 (ushorts), global chunk
    // c = (lane&3) ^ ((row>>1)&3).
    int rowS[2], cG[2], ldsOff[2];
    #pragma unroll
    for (int t = 0; t < 2; ++t) {
        int row = widx * 32 + t * 16 + (lane >> 2);
        rowS[t] = row;
        cG[t] = (lane & 3) ^ ((row >> 1) & 3);
        ldsOff[t] = (widx * 32 + t * 16) * 32 + lane * 8;
    }

    const int nk = K / 32;
    for (int kt = 0; kt < nk; ++kt) {
        const int k0 = kt * 32;
        __syncthreads();   // prior ds_reads done; safe to overwrite LDS
        #pragma unroll
        for (int t = 0; t < 2; ++t) {
            load_lds16(A + (size_t)(m0 + rowS[t]) * K + k0 + cG[t] * 8,
                       &As[ldsOff[t]]);
            load_lds16(BT + (size_t)(n0 + rowS[t]) * K + k0 + cG[t] * 8,
                       &Bs[ldsOff[t]]);
        }
        __syncthreads();   // drains vmcnt -> LDS tile complete

        bf16x8 af[4], bf[4];
        #pragma unroll
        for (int mt = 0; mt < 4; ++mt) {
            int m = wm * 64 + mt * 16 + lm;
            af[mt] = *(const bf16x8*)(&As[m * 32 + ((quad ^ ((m >> 1) & 3)) << 3)]);
        }
        #pragma unroll
        for (int nt = 0; nt < 4; ++nt) {
            int n = wn * 64 + nt * 16 + lm;
            bf[nt] = *(const bf16x8*)(&Bs[n * 32 + ((quad ^ ((n >> 1) & 3)) << 3)]);
        }
        #pragma unroll
        for (int mt = 0; mt < 4; ++mt)
            #pragma unroll
            for (int nt = 0; nt < 4; ++nt)
                acc[mt][nt] = __builtin_amdgcn_mfma_f32_16x16x32_bf16(
                    af[mt], bf[nt], acc[mt][nt], 0, 0, 0);
    }

    float bv[4], scl[4];
    #pragma unroll
    for (int nt = 0; nt < 4; ++nt) {
        bv[nt] = bias[n0 + wn * 64 + nt * 16 + lm];
        scl[nt] = ((n0 + wn * 64 + nt * 16) < scale_cols) ? QSCALE : 1.0f;
    }

    #pragma unroll
    for (int mt = 0; mt < 4; ++mt) {
        #pragma unroll
        for (int nt = 0; nt < 4; ++nt) {
            int col = n0 + wn * 64 + nt * 16 + lm;
            #pragma unroll
            for (int r = 0; r < 4; ++r) {
                int row = m0 + wm * 64 + mt * 16 + quad * 4 + r;
                float v = (acc[mt][nt][r] + bv[nt]) * scl[nt];
                if (OUT_BF16)
                    ((unsigned short*)Cout)[(size_t)row * N + col] = f2b(v);
                else
                    ((float*)Cout)[(size_t)row * N + col] = v;
            }
        }
    }
}

// ---------------------------------------------------------------------------
// MFMA flash attention, dual softmax, no-max (R8-validated kernel) + K tile
// prefetched one iteration ahead (hides L2 latency under softmax+PV).
// P = exp2(s*fs) (masked -> 0 after exp2), state is a pure sum (l, O);
// l via ones-column MFMA; P LDS round-trip for A-frag layout; R7 2-slot
// addition merge tree. LDS: 18432 (Pbuf) + 16896 (Mrg) = 35328 B.
// ---------------------------------------------------------------------------
__global__ __launch_bounds__(256) void attn_mfma(
    const unsigned short* __restrict__ qkv, const unsigned short* __restrict__ VT,
    const float* __restrict__ fsel_arr, const float* __restrict__ lw_p,
    const float* __restrict__ gw_p, unsigned short* __restrict__ attnb)
{
    __shared__ __align__(16) unsigned short Pbuf[4][2][16 * 72];  // 18432 B
    // Mrg[slot][branch][row][0..63 = O cols, 64 = m(=0), 65 = l]
    __shared__ float Mrg[2][2][16][66];                           // 16896 B

    const int tid = threadIdx.x;
    const int widx = tid >> 6, lane = tid & 63;
    const int lm = lane & 15, quad = lane >> 4;

    const int strip = 127 - (int)(blockIdx.x / 24);   // heavy strips first
    const int bh = (int)(blockIdx.x % 24);
    const int h = bh % Hsz, b = bh / Hsz;
    const int i0 = strip * 16;

    unsigned short* Pg = &Pbuf[widx][0][0];
    unsigned short* Pl = &Pbuf[widx][1][0];

    const unsigned short* qkv_b = qkv + (size_t)b * Tsz * C3;

    // Q A-frags: A[m=lm][k=quad*8+j], two k-halves over d=0..63
    const unsigned short* qrow = qkv_b + (size_t)(i0 + lm) * C3 + h * 64 + quad * 8;
    const bf16x8 qf0 = *(const bf16x8*)qrow;
    const bf16x8 qf1 = *(const bf16x8*)(qrow + 32);

    // ones B-frag: B[k][0] = 1 (lanes with lm==0), else 0 -> P*B col0 = row sum
    const short o1 = (lm == 0) ? (short)0x3F80 : (short)0;
    const bf16x8 of = bf16x8{o1, o1, o1, o1, o1, o1, o1, o1};

    float m_g[4], l_g[4], m_l[4], l_l[4];      // m pinned at 0 (no-max)
    f32x4 Og[4], Ol[4], lsg, lsl;
    #pragma unroll
    for (int r = 0; r < 4; ++r) {
        m_g[r] = 0.f; m_l[r] = 0.f;
        l_g[r] = 0.f; l_l[r] = 0.f;
    }
    #pragma unroll
    for (int nt = 0; nt < 4; ++nt) {
        Og[nt] = f32x4{0.f, 0.f, 0.f, 0.f};
        Ol[nt] = f32x4{0.f, 0.f, 0.f, 0.f};
    }
    lsg = f32x4{0.f, 0.f, 0.f, 0.f};
    lsl = f32x4{0.f, 0.f, 0.f, 0.f};

    const int jtd = i0 >> 6;                        // diagonal 64-tile
    const int jtl = (jtd - 4) > 0 ? (jtd - 4) : 0;  // first local tile

    // K B-frags for this wave's first tile, prefetched
    bf16x8 kf[4][2];
    if (widx <= jtd) {
        const unsigned short* kb =
            qkv_b + (size_t)(widx * 64 + lm) * C3 + Csz + h * 64 + quad * 8;
        #pragma unroll
        for (int nt = 0; nt < 4; ++nt) {
            kf[nt][0] = *(const bf16x8*)(kb + (size_t)nt * 16 * C3);
            kf[nt][1] = *(const bf16x8*)(kb + (size_t)nt * 16 * C3 + 32);
        }
    }

    for (int jt = widx; jt <= jtd; jt += 4) {
        const int j0 = jt * 64;
        const bool diag = (jt == jtd);
        const bool loc = (jt >= jtl);

        // ---- QK^T from prefetched K frags ----
        f32x4 s[4];
        #pragma unroll
        for (int nt = 0; nt < 4; ++nt) {
            f32x4 z = f32x4{0.f, 0.f, 0.f, 0.f};
            z = __builtin_amdgcn_mfma_f32_16x16x32_bf16(qf0, kf[nt][0], z, 0, 0, 0);
            z = __builtin_amdgcn_mfma_f32_16x16x32_bf16(qf1, kf[nt][1], z, 0, 0, 0);
            s[nt] = z;
        }

        // ---- prefetch next K tile (overlaps softmax + PV below) ----
        if (jt + 4 <= jtd) {
            const unsigned short* kb =
                qkv_b + (size_t)(j0 + 256 + lm) * C3 + Csz + h * 64 + quad * 8;
            #pragma unroll
            for (int nt = 0; nt < 4; ++nt) {
                kf[nt][0] = *(const bf16x8*)(kb + (size_t)nt * 16 * C3);
                kf[nt][1] = *(const bf16x8*)(kb + (size_t)nt * 16 * C3 + 32);
            }
        }

        float fs[4];
        #pragma unroll
        for (int nt = 0; nt < 4; ++nt)
            fs[nt] = fsel_arr[b * Tsz + j0 + nt * 16 + lm];

        // ---- global branch: P = exp2(s*fs), causal mask -> 0 on diag ----
        if (diag) {
            #pragma unroll
            for (int r = 0; r < 4; ++r) {
                const int qi = i0 + quad * 4 + r;
                #pragma unroll
                for (int nt = 0; nt < 4; ++nt) {
                    const int kj = j0 + nt * 16 + lm;
                    float p = exp2f(s[nt][r] * fs[nt]);
                    p = (kj > qi) ? 0.f : p;
                    Pg[(quad * 4 + r) * 72 + nt * 16 + lm] = f2b_trunc(p);
                }
            }
        } else {
            #pragma unroll
            for (int r = 0; r < 4; ++r)
                #pragma unroll
                for (int nt = 0; nt < 4; ++nt)
                    Pg[(quad * 4 + r) * 72 + nt * 16 + lm] =
                        f2b_trunc(exp2f(s[nt][r] * fs[nt]));
        }

        // ---- local branch: P = exp2(s), window+causal mask -> 0 ----
        if (loc) {
            #pragma unroll
            for (int r = 0; r < 4; ++r) {
                const int qi = i0 + quad * 4 + r;
                #pragma unroll
                for (int nt = 0; nt < 4; ++nt) {
                    const int kj = j0 + nt * 16 + lm;
                    float p = exp2f(s[nt][r]);
                    p = (kj > qi || kj < qi - WIN) ? 0.f : p;
                    Pl[(quad * 4 + r) * 72 + nt * 16 + lm] = f2b_trunc(p);
                }
            }
        }

        // ---- P A-frags (same-wave LDS round-trip); l + PV via MFMA ----
        const bf16x8 ag0 = *(const bf16x8*)(&Pg[lm * 72 + quad * 8]);
        const bf16x8 ag1 = *(const bf16x8*)(&Pg[lm * 72 + 32 + quad * 8]);
        const unsigned short* vb =
            VT + ((size_t)bh * 64 + lm) * Tsz + j0 + quad * 8;
        lsg = __builtin_amdgcn_mfma_f32_16x16x32_bf16(ag0, of, lsg, 0, 0, 0);
        lsg = __builtin_amdgcn_mfma_f32_16x16x32_bf16(ag1, of, lsg, 0, 0, 0);
        #pragma unroll
        for (int nt = 0; nt < 4; ++nt) {
            bf16x8 v0 = *(const bf16x8*)(vb + (size_t)nt * 16 * Tsz);
            bf16x8 v1 = *(const bf16x8*)(vb + (size_t)nt * 16 * Tsz + 32);
            Og[nt] = __builtin_amdgcn_mfma_f32_16x16x32_bf16(ag0, v0, Og[nt], 0, 0, 0);
            Og[nt] = __builtin_amdgcn_mfma_f32_16x16x32_bf16(ag1, v1, Og[nt], 0, 0, 0);
            if (loc) {
                const bf16x8 al0 = *(const bf16x8*)(&Pl[lm * 72 + quad * 8]);
                const bf16x8 al1 = *(const bf16x8*)(&Pl[lm * 72 + 32 + quad * 8]);
                Ol[nt] = __builtin_amdgcn_mfma_f32_16x16x32_bf16(al0, v0, Ol[nt], 0, 0, 0);
                Ol[nt] = __builtin_amdgcn_mfma_f32_16x16x32_bf16(al1, v1, Ol[nt], 0, 0, 0);
            }
        }
        if (loc) {
            const bf16x8 al0 = *(const bf16x8*)(&Pl[lm * 72 + quad * 8]);
            const bf16x8 al1 = *(const bf16x8*)(&Pl[lm * 72 + 32 + quad * 8]);
            lsl = __builtin_amdgcn_mfma_f32_16x16x32_bf16(al0, of, lsl, 0, 0, 0);
            lsl = __builtin_amdgcn_mfma_f32_16x16x32_bf16(al1, of, lsl, 0, 0, 0);
        }
    }

    // fold MFMA l (valid in lanes lm==0) into the scalar l state
    #pragma unroll
    for (int r = 0; r < 4; ++r) { l_g[r] = lsg[r]; l_l[r] = lsl[r]; }

    // ==== 2-slot pairwise merge tree (pure sums) ====
    auto write_slot = [&](int slot) {
        #pragma unroll
        for (int r = 0; r < 4; ++r) {
            const int row = quad * 4 + r;
            #pragma unroll
            for (int nt = 0; nt < 4; ++nt) {
                Mrg[slot][0][row][nt * 16 + lm] = Og[nt][r];
                Mrg[slot][1][row][nt * 16 + lm] = Ol[nt][r];
            }
            if (lm == 0) {
                Mrg[slot][0][row][64] = m_g[r];
                Mrg[slot][0][row][65] = l_g[r];
                Mrg[slot][1][row][64] = m_l[r];
                Mrg[slot][1][row][65] = l_l[r];
            }
        }
    };
    auto combine_slot = [&](int slot) {
        #pragma unroll
        for (int r = 0; r < 4; ++r) {
            const int row = quad * 4 + r;
            {
                float ls = Mrg[slot][0][row][65];
                l_g[r] = l_g[r] + ls;
                #pragma unroll
                for (int nt = 0; nt < 4; ++nt)
                    Og[nt][r] += Mrg[slot][0][row][nt * 16 + lm];
            }
            {
                float ls = Mrg[slot][1][row][65];
                l_l[r] = l_l[r] + ls;
                #pragma unroll
                for (int nt = 0; nt < 4; ++nt)
                    Ol[nt][r] += Mrg[slot][1][row][nt * 16 + lm];
            }
        }
    };

    if (widx == 1) write_slot(0);
    if (widx == 3) write_slot(1);
    __syncthreads();
    if (widx == 0) combine_slot(0);
    if (widx == 2) combine_slot(1);
    __syncthreads();
    if (widx == 2) write_slot(0);
    __syncthreads();

    if (widx == 0) {
        combine_slot(0);      // wave 0 now holds the full-strip sums

        // broadcast l from lanes lm==0 (MFMA row-sum column) to all lanes
        #pragma unroll
        for (int r = 0; r < 4; ++r) {
            l_g[r] = __shfl(l_g[r], quad << 4);
            l_l[r] = __shfl(l_l[r], quad << 4);
        }

        float wl = 1.f / (1.f + __expf(-lw_p[0]));
        float wg = 1.f / (1.f + __expf(-gw_p[0]));
        float ws = wl + wg;
        wl /= ws; wg /= ws;

        #pragma unroll
        for (int r = 0; r < 4; ++r) {
            const int row = quad * 4 + r;
            const float cg = wg / l_g[r];
            const float cl = wl / l_l[r];
            #pragma unroll
            for (int nt = 0; nt < 4; ++nt) {
                float v = Og[nt][r] * cg + Ol[nt][r] * cl;
                attnb[(size_t)(b * Tsz + i0 + row) * Csz + h * 64 + nt * 16 + lm] =
                    f2b(v);
            }
        }
    }
}

// ---------------------------------------------------------------------------
extern "C" void kernel_launch(void* const* d_in, const int* in_sizes, int n_in,
                              void* d_out, int out_size, void* d_ws, size_t ws_size,
                              hipStream_t stream)
{
    const float* x          = (const float*)d_in[0];
    const float* mamba_raw  = (const float*)d_in[1];
    const float* c_attn_w   = (const float*)d_in[2];
    const float* c_attn_b   = (const float*)d_in[3];
    const float* c_proj_w   = (const float*)d_in[4];
    const float* c_proj_b   = (const float*)d_in[5];
    const float* ln_w       = (const float*)d_in[6];
    const float* ln_b       = (const float*)d_in[7];
    const float* mamba_sc   = (const float*)d_in[8];
    const float* sel_w      = (const float*)d_in[9];
    const float* sel_b      = (const float*)d_in[10];
    const float* local_w    = (const float*)d_in[11];
    const float* global_w   = (const float*)d_in[12];
    float* out = (float*)d_out;

    const int M = Bsz * Tsz;                 // 4096

    // Workspace layout (ushort units)
    unsigned short* xb    = (unsigned short*)d_ws;       // 4096*768
    unsigned short* wq    = xb + (size_t)M * Csz;        // 2304*768 (c_attn_w^T)
    unsigned short* wp    = wq + (size_t)C3 * Csz;       // 768*768  (c_proj_w^T)
    unsigned short* qkvb  = wp + (size_t)Csz * Csz;      // 4096*2304
    unsigned short* vt    = qkvb + (size_t)M * C3;       // 24*64*2048
    unsigned short* attnb = vt + (size_t)Bsz * Hsz * 64 * Tsz; // 4096*768
    float* sel = (float*)(attnb + (size_t)M * Csz);      // 4096

    // 1) conversions
    convert_bf16<<<(M * Csz / 4 + 255) / 256, 256, 0, stream>>>(x, xb, M * Csz / 4);
    {
        dim3 g(C3 / 32, Csz / 32);
        transpose_conv<<<g, 256, 0, stream>>>(c_attn_w, wq, Csz, C3);
    }
    {
        dim3 g(Csz / 32, Csz / 32);
        transpose_conv<<<g, 256, 0, stream>>>(c_proj_w, wp, Csz, Csz);
    }

    // 2) selector (outputs 0.5 + 0.5*sigmoid)
    sel_kernel<<<M, 256, 0, stream>>>(mamba_raw, ln_w, ln_b, mamba_sc,
                                      sel_w, sel_b, sel);

    // 3) QKV projection (bf16 out; Q cols pre-scaled by QSCALE)
    {
        dim3 g(C3 / 128, M / 128);
        gemm_bt_mfma<1><<<g, 256, 0, stream>>>(xb, wq, c_attn_b, qkvb,
                                               M, C3, Csz, Csz);
    }

    // 4) V transpose
    {
        dim3 g(Tsz / 32, 64 / 32, Bsz * Hsz);
        transpose_v<<<g, 256, 0, stream>>>(qkvb, vt);
    }

    // 5) attention (bf16 out): one block per strip per (b,h)
    attn_mfma<<<128 * Hsz * Bsz, 256, 0, stream>>>(qkvb, vt, sel,
                                                   local_w, global_w, attnb);

    // 6) output projection (fp32 out, no scaling)
    {
        dim3 g(Csz / 128, M / 128);
        gemm_bt_mfma<0><<<g, 256, 0, stream>>>(attnb, wp, c_proj_b, out,
                                               M, Csz, Csz, 0);
    }
}

// Round 11
// 258.736 us; speedup vs baseline: 1.1774x; 1.0628x over previous
//
#include <hip/hip_runtime.h>
#include <math.h>

// Problem constants
#define Bsz 2
#define Tsz 2048
#define Csz 768
#define Hsz 12
#define C3  2304      // 3*C
#define WIN 256
#define LN_EPS 1e-5f

// Q pre-scale: D^-0.5 * log2(e), folded into the QKV GEMM epilogue so the
// attention kernel works in the exp2 domain with no per-element multiplies.
#define QSCALE 0.1803368801111137f

typedef short bf16x8 __attribute__((ext_vector_type(8)));  // 8 bf16 (4 VGPRs)
typedef float f32x4  __attribute__((ext_vector_type(4)));

// fp32 -> bf16 round-to-nearest-even
__device__ __forceinline__ unsigned short f2b(float f) {
    unsigned int u = __float_as_uint(f);
    u = (u + 0x7fffu + ((u >> 16) & 1u)) >> 16;
    return (unsigned short)u;
}
// fp32 -> bf16 truncation (1 op; P>=0 and l self-normalizes, bias cancels)
__device__ __forceinline__ unsigned short f2b_trunc(float f) {
    return (unsigned short)(__float_as_uint(f) >> 16);
}

// ---------------------------------------------------------------------------
// Elementwise fp32 -> bf16 (4 elems/thread)
// ---------------------------------------------------------------------------
__global__ __launch_bounds__(256) void convert_bf16(
    const float* __restrict__ src, unsigned short* __restrict__ dst, int n4)
{
    int idx = blockIdx.x * 256 + threadIdx.x;
    if (idx >= n4) return;
    float4 v = *(const float4*)(src + (size_t)idx * 4);
    unsigned int lo = (unsigned int)f2b(v.x) | ((unsigned int)f2b(v.y) << 16);
    unsigned int hi = (unsigned int)f2b(v.z) | ((unsigned int)f2b(v.w) << 16);
    uint2 o; o.x = lo; o.y = hi;
    *(uint2*)(dst + (size_t)idx * 4) = o;
}

// ---------------------------------------------------------------------------
// fp32 [K][N] -> bf16 [N][K] (transpose + convert)
// ---------------------------------------------------------------------------
__global__ __launch_bounds__(256) void transpose_conv(
    const float* __restrict__ src, unsigned short* __restrict__ dst, int K, int N)
{
    __shared__ float tile[32][33];
    const int n0 = blockIdx.x * 32, k0 = blockIdx.y * 32;
    const int tx = threadIdx.x & 31, ty = threadIdx.x >> 5;   // 32 x 8
    #pragma unroll
    for (int p = 0; p < 4; ++p)
        tile[ty + p * 8][tx] = src[(size_t)(k0 + ty + p * 8) * N + n0 + tx];
    __syncthreads();
    #pragma unroll
    for (int p = 0; p < 4; ++p)
        dst[(size_t)(n0 + ty + p * 8) * K + k0 + tx] = f2b(tile[tx][ty + p * 8]);
}

// ---------------------------------------------------------------------------
// V transpose: qkvb bf16 [B*T][3C] -> VT bf16 [B*H][64][T]
// ---------------------------------------------------------------------------
__global__ __launch_bounds__(256) void transpose_v(
    const unsigned short* __restrict__ qkv, unsigned short* __restrict__ VT)
{
    __shared__ unsigned short tile[32][33];
    const int bh = blockIdx.z;
    const int b = bh / Hsz, h = bh % Hsz;
    const int t0 = blockIdx.x * 32, d0 = blockIdx.y * 32;
    const int tx = threadIdx.x & 31, ty = threadIdx.x >> 5;
    #pragma unroll
    for (int p = 0; p < 4; ++p) {
        int t = t0 + ty + p * 8;
        tile[ty + p * 8][tx] =
            qkv[(size_t)(b * Tsz + t) * C3 + 2 * Csz + h * 64 + d0 + tx];
    }
    __syncthreads();
    #pragma unroll
    for (int p = 0; p < 4; ++p) {
        int d = d0 + ty + p * 8;
        VT[((size_t)bh * 64 + d) * Tsz + t0 + tx] = tile[tx][ty + p * 8];
    }
}

// ---------------------------------------------------------------------------
// fsel[r] = 0.5 + 0.5*sigmoid(mamba_scale * dot(LN(mamba_raw[r]), sel_w) + sel_b)
// ---------------------------------------------------------------------------
__global__ __launch_bounds__(256) void sel_kernel(
    const float* __restrict__ mr, const float* __restrict__ ln_w,
    const float* __restrict__ ln_b, const float* __restrict__ scale_p,
    const float* __restrict__ sel_w, const float* __restrict__ sel_b,
    float* __restrict__ sel)
{
    __shared__ float red1[256];
    __shared__ float red2[256];
    __shared__ float mu_sh, rstd_sh;

    const int r = blockIdx.x;
    const int tid = threadIdx.x;
    const float* row = mr + (size_t)r * Csz;

    float s = 0.f, s2 = 0.f;
    for (int c = tid; c < Csz; c += 256) {
        float x = row[c];
        s += x; s2 += x * x;
    }
    red1[tid] = s; red2[tid] = s2;
    __syncthreads();
    for (int st = 128; st > 0; st >>= 1) {
        if (tid < st) { red1[tid] += red1[tid + st]; red2[tid] += red2[tid + st]; }
        __syncthreads();
    }
    if (tid == 0) {
        float mu = red1[0] * (1.f / Csz);
        float var = red2[0] * (1.f / Csz) - mu * mu;
        mu_sh = mu;
        rstd_sh = rsqrtf(var + LN_EPS);
    }
    __syncthreads();
    const float mu = mu_sh, rstd = rstd_sh;

    float dot = 0.f;
    for (int c = tid; c < Csz; c += 256) {
        float xn = (row[c] - mu) * rstd * ln_w[c] + ln_b[c];
        dot += xn * sel_w[c];
    }
    red1[tid] = dot;
    __syncthreads();
    for (int st = 128; st > 0; st >>= 1) {
        if (tid < st) red1[tid] += red1[tid + st];
        __syncthreads();
    }
    if (tid == 0) {
        float z = scale_p[0] * red1[0] + sel_b[0];
        sel[r] = 0.5f + 0.5f / (1.f + __expf(-z));
    }
}

// ---------------------------------------------------------------------------
// bf16 MFMA GEMM, B^T input: C[M,N] = A[M,K] @ BT[N,K]^T + bias
// (R8 version: register-prefetch double buffer -- R10's global_load_lds
// variant regressed ~11 us because it dropped this overlap.)
// cols < scale_cols additionally scaled by QSCALE (folds attention q-scale).
// ---------------------------------------------------------------------------
template<int OUT_BF16>
__global__ __launch_bounds__(256) void gemm_bt_mfma(
    const unsigned short* __restrict__ A, const unsigned short* __restrict__ BT,
    const float* __restrict__ bias, void* __restrict__ Cout,
    int M, int N, int K, int scale_cols)
{
    __shared__ unsigned short As[128 * 32];
    __shared__ unsigned short Bs[128 * 32];

    const int tid = threadIdx.x;
    const int lane = tid & 63, widx = tid >> 6;
    const int lm = lane & 15, quad = lane >> 4;
    const int wm = widx >> 1, wn = widx & 1;
    const int m0 = blockIdx.y * 128, n0 = blockIdx.x * 128;

    f32x4 acc[4][4];
    #pragma unroll
    for (int mt = 0; mt < 4; ++mt)
        #pragma unroll
        for (int nt = 0; nt < 4; ++nt)
            acc[mt][nt] = f32x4{0.f, 0.f, 0.f, 0.f};

    int rowS[2], cS[2];
    #pragma unroll
    for (int t = 0; t < 2; ++t) {
        int idx = t * 256 + tid;
        rowS[t] = idx >> 2;
        cS[t] = idx & 3;
    }

    bf16x8 pa[2], pb[2];
    #pragma unroll
    for (int t = 0; t < 2; ++t) {
        pa[t] = *(const bf16x8*)(A + (size_t)(m0 + rowS[t]) * K + cS[t] * 8);
        pb[t] = *(const bf16x8*)(BT + (size_t)(n0 + rowS[t]) * K + cS[t] * 8);
    }

    const int nk = K / 32;
    for (int kt = 0; kt < nk; ++kt) {
        __syncthreads();
        #pragma unroll
        for (int t = 0; t < 2; ++t) {
            *(bf16x8*)(&As[rowS[t] * 32 + ((cS[t] ^ ((rowS[t] >> 1) & 3)) << 3)]) = pa[t];
            *(bf16x8*)(&Bs[rowS[t] * 32 + ((cS[t] ^ ((rowS[t] >> 1) & 3)) << 3)]) = pb[t];
        }
        __syncthreads();
        if (kt + 1 < nk) {
            int k0 = (kt + 1) * 32;
            #pragma unroll
            for (int t = 0; t < 2; ++t) {
                pa[t] = *(const bf16x8*)(A + (size_t)(m0 + rowS[t]) * K + k0 + cS[t] * 8);
                pb[t] = *(const bf16x8*)(BT + (size_t)(n0 + rowS[t]) * K + k0 + cS[t] * 8);
            }
        }
        bf16x8 af[4], bf[4];
        #pragma unroll
        for (int mt = 0; mt < 4; ++mt) {
            int m = wm * 64 + mt * 16 + lm;
            af[mt] = *(const bf16x8*)(&As[m * 32 + ((quad ^ ((m >> 1) & 3)) << 3)]);
        }
        #pragma unroll
        for (int nt = 0; nt < 4; ++nt) {
            int n = wn * 64 + nt * 16 + lm;
            bf[nt] = *(const bf16x8*)(&Bs[n * 32 + ((quad ^ ((n >> 1) & 3)) << 3)]);
        }
        #pragma unroll
        for (int mt = 0; mt < 4; ++mt)
            #pragma unroll
            for (int nt = 0; nt < 4; ++nt)
                acc[mt][nt] = __builtin_amdgcn_mfma_f32_16x16x32_bf16(
                    af[mt], bf[nt], acc[mt][nt], 0, 0, 0);
    }

    float bv[4], scl[4];
    #pragma unroll
    for (int nt = 0; nt < 4; ++nt) {
        bv[nt] = bias[n0 + wn * 64 + nt * 16 + lm];
        scl[nt] = ((n0 + wn * 64 + nt * 16) < scale_cols) ? QSCALE : 1.0f;
    }

    #pragma unroll
    for (int mt = 0; mt < 4; ++mt) {
        #pragma unroll
        for (int nt = 0; nt < 4; ++nt) {
            int col = n0 + wn * 64 + nt * 16 + lm;
            #pragma unroll
            for (int r = 0; r < 4; ++r) {
                int row = m0 + wm * 64 + mt * 16 + quad * 4 + r;
                float v = (acc[mt][nt][r] + bv[nt]) * scl[nt];
                if (OUT_BF16)
                    ((unsigned short*)Cout)[(size_t)row * N + col] = f2b(v);
                else
                    ((float*)Cout)[(size_t)row * N + col] = v;
            }
        }
    }
}

// ---------------------------------------------------------------------------
// MFMA flash attention, dual softmax, no-max (R8-validated inner loop).
// R11: Pbuf (loop phase, 18432 B) and Mrg (merge phase, 16896 B) are
// temporally disjoint -- they now ALIAS one 18432 B allocation (union sized
// by the max; the existing __syncthreads separates the phases). LDS/block
// 35328 -> 18432 B lifts occupancy cap 4 -> ~7 blocks/CU (VGPR 72-bound).
// ---------------------------------------------------------------------------
__global__ __launch_bounds__(256) void attn_mfma(
    const unsigned short* __restrict__ qkv, const unsigned short* __restrict__ VT,
    const float* __restrict__ fsel_arr, const float* __restrict__ lw_p,
    const float* __restrict__ gw_p, unsigned short* __restrict__ attnb)
{
    // Union: loop phase uses Pbuf[4 waves][2 branches][16*72 ushorts];
    // merge phase uses Mrg[2 slots][2 branches][16][66 floats] (16896 B).
    __shared__ __align__(16) unsigned char ShRaw[18432];
    typedef float MrgT[2][16][66];
    MrgT* Mrg = reinterpret_cast<MrgT*>(ShRaw);     // Mrg[slot][br][row][col]

    const int tid = threadIdx.x;
    const int widx = tid >> 6, lane = tid & 63;
    const int lm = lane & 15, quad = lane >> 4;

    const int strip = 127 - (int)(blockIdx.x / 24);   // heavy strips first
    const int bh = (int)(blockIdx.x % 24);
    const int h = bh % Hsz, b = bh / Hsz;
    const int i0 = strip * 16;

    unsigned short* Pg = (unsigned short*)ShRaw + widx * (2 * 16 * 72);
    unsigned short* Pl = Pg + 16 * 72;

    const unsigned short* qkv_b = qkv + (size_t)b * Tsz * C3;

    // Q A-frags: A[m=lm][k=quad*8+j], two k-halves over d=0..63
    const unsigned short* qrow = qkv_b + (size_t)(i0 + lm) * C3 + h * 64 + quad * 8;
    const bf16x8 qf0 = *(const bf16x8*)qrow;
    const bf16x8 qf1 = *(const bf16x8*)(qrow + 32);

    // ones B-frag: B[k][0] = 1 (lanes with lm==0), else 0 -> P*B col0 = row sum
    const short o1 = (lm == 0) ? (short)0x3F80 : (short)0;
    const bf16x8 of = bf16x8{o1, o1, o1, o1, o1, o1, o1, o1};

    float m_g[4], l_g[4], m_l[4], l_l[4];      // m pinned at 0 (no-max)
    f32x4 Og[4], Ol[4], lsg, lsl;
    #pragma unroll
    for (int r = 0; r < 4; ++r) {
        m_g[r] = 0.f; m_l[r] = 0.f;
        l_g[r] = 0.f; l_l[r] = 0.f;
    }
    #pragma unroll
    for (int nt = 0; nt < 4; ++nt) {
        Og[nt] = f32x4{0.f, 0.f, 0.f, 0.f};
        Ol[nt] = f32x4{0.f, 0.f, 0.f, 0.f};
    }
    lsg = f32x4{0.f, 0.f, 0.f, 0.f};
    lsl = f32x4{0.f, 0.f, 0.f, 0.f};

    const int jtd = i0 >> 6;                        // diagonal 64-tile
    const int jtl = (jtd - 4) > 0 ? (jtd - 4) : 0;  // first local tile

    for (int jt = widx; jt <= jtd; jt += 4) {
        const int j0 = jt * 64;
        const bool diag = (jt == jtd);
        const bool loc = (jt >= jtl);

        // ---- QK^T: K B-frags direct from global ----
        const unsigned short* kb =
            qkv_b + (size_t)(j0 + lm) * C3 + Csz + h * 64 + quad * 8;
        f32x4 s[4];
        #pragma unroll
        for (int nt = 0; nt < 4; ++nt) {
            bf16x8 k0v = *(const bf16x8*)(kb + (size_t)nt * 16 * C3);
            bf16x8 k1v = *(const bf16x8*)(kb + (size_t)nt * 16 * C3 + 32);
            f32x4 z = f32x4{0.f, 0.f, 0.f, 0.f};
            z = __builtin_amdgcn_mfma_f32_16x16x32_bf16(qf0, k0v, z, 0, 0, 0);
            z = __builtin_amdgcn_mfma_f32_16x16x32_bf16(qf1, k1v, z, 0, 0, 0);
            s[nt] = z;
        }

        float fs[4];
        #pragma unroll
        for (int nt = 0; nt < 4; ++nt)
            fs[nt] = fsel_arr[b * Tsz + j0 + nt * 16 + lm];

        // ---- global branch: P = exp2(s*fs), causal mask -> 0 on diag ----
        if (diag) {
            #pragma unroll
            for (int r = 0; r < 4; ++r) {
                const int qi = i0 + quad * 4 + r;
                #pragma unroll
                for (int nt = 0; nt < 4; ++nt) {
                    const int kj = j0 + nt * 16 + lm;
                    float p = exp2f(s[nt][r] * fs[nt]);
                    p = (kj > qi) ? 0.f : p;
                    Pg[(quad * 4 + r) * 72 + nt * 16 + lm] = f2b_trunc(p);
                }
            }
        } else {
            #pragma unroll
            for (int r = 0; r < 4; ++r)
                #pragma unroll
                for (int nt = 0; nt < 4; ++nt)
                    Pg[(quad * 4 + r) * 72 + nt * 16 + lm] =
                        f2b_trunc(exp2f(s[nt][r] * fs[nt]));
        }

        // ---- local branch: P = exp2(s), window+causal mask -> 0 ----
        if (loc) {
            #pragma unroll
            for (int r = 0; r < 4; ++r) {
                const int qi = i0 + quad * 4 + r;
                #pragma unroll
                for (int nt = 0; nt < 4; ++nt) {
                    const int kj = j0 + nt * 16 + lm;
                    float p = exp2f(s[nt][r]);
                    p = (kj > qi || kj < qi - WIN) ? 0.f : p;
                    Pl[(quad * 4 + r) * 72 + nt * 16 + lm] = f2b_trunc(p);
                }
            }
        }

        // ---- P A-frags (same-wave LDS round-trip); l + PV via MFMA ----
        const bf16x8 ag0 = *(const bf16x8*)(&Pg[lm * 72 + quad * 8]);
        const bf16x8 ag1 = *(const bf16x8*)(&Pg[lm * 72 + 32 + quad * 8]);
        const unsigned short* vb =
            VT + ((size_t)bh * 64 + lm) * Tsz + j0 + quad * 8;
        lsg = __builtin_amdgcn_mfma_f32_16x16x32_bf16(ag0, of, lsg, 0, 0, 0);
        lsg = __builtin_amdgcn_mfma_f32_16x16x32_bf16(ag1, of, lsg, 0, 0, 0);
        #pragma unroll
        for (int nt = 0; nt < 4; ++nt) {
            bf16x8 v0 = *(const bf16x8*)(vb + (size_t)nt * 16 * Tsz);
            bf16x8 v1 = *(const bf16x8*)(vb + (size_t)nt * 16 * Tsz + 32);
            Og[nt] = __builtin_amdgcn_mfma_f32_16x16x32_bf16(ag0, v0, Og[nt], 0, 0, 0);
            Og[nt] = __builtin_amdgcn_mfma_f32_16x16x32_bf16(ag1, v1, Og[nt], 0, 0, 0);
            if (loc) {
                const bf16x8 al0 = *(const bf16x8*)(&Pl[lm * 72 + quad * 8]);
                const bf16x8 al1 = *(const bf16x8*)(&Pl[lm * 72 + 32 + quad * 8]);
                Ol[nt] = __builtin_amdgcn_mfma_f32_16x16x32_bf16(al0, v0, Ol[nt], 0, 0, 0);
                Ol[nt] = __builtin_amdgcn_mfma_f32_16x16x32_bf16(al1, v1, Ol[nt], 0, 0, 0);
            }
        }
        if (loc) {
            const bf16x8 al0 = *(const bf16x8*)(&Pl[lm * 72 + quad * 8]);
            const bf16x8 al1 = *(const bf16x8*)(&Pl[lm * 72 + 32 + quad * 8]);
            lsl = __builtin_amdgcn_mfma_f32_16x16x32_bf16(al0, of, lsl, 0, 0, 0);
            lsl = __builtin_amdgcn_mfma_f32_16x16x32_bf16(al1, of, lsl, 0, 0, 0);
        }
    }

    // fold MFMA l (valid in lanes lm==0) into the scalar l state
    #pragma unroll
    for (int r = 0; r < 4; ++r) { l_g[r] = lsg[r]; l_l[r] = lsl[r]; }

    // ==== 2-slot pairwise merge tree (pure sums; Mrg aliases Pbuf) ====
    __syncthreads();   // all waves done reading their P strips

    auto write_slot = [&](int slot) {
        #pragma unroll
        for (int r = 0; r < 4; ++r) {
            const int row = quad * 4 + r;
            #pragma unroll
            for (int nt = 0; nt < 4; ++nt) {
                Mrg[slot][0][row][nt * 16 + lm] = Og[nt][r];
                Mrg[slot][1][row][nt * 16 + lm] = Ol[nt][r];
            }
            if (lm == 0) {
                Mrg[slot][0][row][64] = m_g[r];
                Mrg[slot][0][row][65] = l_g[r];
                Mrg[slot][1][row][64] = m_l[r];
                Mrg[slot][1][row][65] = l_l[r];
            }
        }
    };
    auto combine_slot = [&](int slot) {
        #pragma unroll
        for (int r = 0; r < 4; ++r) {
            const int row = quad * 4 + r;
            {
                float ls = Mrg[slot][0][row][65];
                l_g[r] = l_g[r] + ls;
                #pragma unroll
                for (int nt = 0; nt < 4; ++nt)
                    Og[nt][r] += Mrg[slot][0][row][nt * 16 + lm];
            }
            {
                float ls = Mrg[slot][1][row][65];
                l_l[r] = l_l[r] + ls;
                #pragma unroll
                for (int nt = 0; nt < 4; ++nt)
                    Ol[nt][r] += Mrg[slot][1][row][nt * 16 + lm];
            }
        }
    };

    if (widx == 1) write_slot(0);
    if (widx == 3) write_slot(1);
    __syncthreads();
    if (widx == 0) combine_slot(0);
    if (widx == 2) combine_slot(1);
    __syncthreads();
    if (widx == 2) write_slot(0);
    __syncthreads();

    if (widx == 0) {
        combine_slot(0);      // wave 0 now holds the full-strip sums

        // broadcast l from lanes lm==0 (MFMA row-sum column) to all lanes
        #pragma unroll
        for (int r = 0; r < 4; ++r) {
            l_g[r] = __shfl(l_g[r], quad << 4);
            l_l[r] = __shfl(l_l[r], quad << 4);
        }

        float wl = 1.f / (1.f + __expf(-lw_p[0]));
        float wg = 1.f / (1.f + __expf(-gw_p[0]));
        float ws = wl + wg;
        wl /= ws; wg /= ws;

        #pragma unroll
        for (int r = 0; r < 4; ++r) {
            const int row = quad * 4 + r;
            const float cg = wg / l_g[r];
            const float cl = wl / l_l[r];
            #pragma unroll
            for (int nt = 0; nt < 4; ++nt) {
                float v = Og[nt][r] * cg + Ol[nt][r] * cl;
                attnb[(size_t)(b * Tsz + i0 + row) * Csz + h * 64 + nt * 16 + lm] =
                    f2b(v);
            }
        }
    }
}

// ---------------------------------------------------------------------------
extern "C" void kernel_launch(void* const* d_in, const int* in_sizes, int n_in,
                              void* d_out, int out_size, void* d_ws, size_t ws_size,
                              hipStream_t stream)
{
    const float* x          = (const float*)d_in[0];
    const float* mamba_raw  = (const float*)d_in[1];
    const float* c_attn_w   = (const float*)d_in[2];
    const float* c_attn_b   = (const float*)d_in[3];
    const float* c_proj_w   = (const float*)d_in[4];
    const float* c_proj_b   = (const float*)d_in[5];
    const float* ln_w       = (const float*)d_in[6];
    const float* ln_b       = (const float*)d_in[7];
    const float* mamba_sc   = (const float*)d_in[8];
    const float* sel_w      = (const float*)d_in[9];
    const float* sel_b      = (const float*)d_in[10];
    const float* local_w    = (const float*)d_in[11];
    const float* global_w   = (const float*)d_in[12];
    float* out = (float*)d_out;

    const int M = Bsz * Tsz;                 // 4096

    // Workspace layout (ushort units)
    unsigned short* xb    = (unsigned short*)d_ws;       // 4096*768
    unsigned short* wq    = xb + (size_t)M * Csz;        // 2304*768 (c_attn_w^T)
    unsigned short* wp    = wq + (size_t)C3 * Csz;       // 768*768  (c_proj_w^T)
    unsigned short* qkvb  = wp + (size_t)Csz * Csz;      // 4096*2304
    unsigned short* vt    = qkvb + (size_t)M * C3;       // 24*64*2048
    unsigned short* attnb = vt + (size_t)Bsz * Hsz * 64 * Tsz; // 4096*768
    float* sel = (float*)(attnb + (size_t)M * Csz);      // 4096

    // 1) conversions
    convert_bf16<<<(M * Csz / 4 + 255) / 256, 256, 0, stream>>>(x, xb, M * Csz / 4);
    {
        dim3 g(C3 / 32, Csz / 32);
        transpose_conv<<<g, 256, 0, stream>>>(c_attn_w, wq, Csz, C3);
    }
    {
        dim3 g(Csz / 32, Csz / 32);
        transpose_conv<<<g, 256, 0, stream>>>(c_proj_w, wp, Csz, Csz);
    }

    // 2) selector (outputs 0.5 + 0.5*sigmoid)
    sel_kernel<<<M, 256, 0, stream>>>(mamba_raw, ln_w, ln_b, mamba_sc,
                                      sel_w, sel_b, sel);

    // 3) QKV projection (bf16 out; Q cols pre-scaled by QSCALE)
    {
        dim3 g(C3 / 128, M / 128);
        gemm_bt_mfma<1><<<g, 256, 0, stream>>>(xb, wq, c_attn_b, qkvb,
                                               M, C3, Csz, Csz);
    }

    // 4) V transpose
    {
        dim3 g(Tsz / 32, 64 / 32, Bsz * Hsz);
        transpose_v<<<g, 256, 0, stream>>>(qkvb, vt);
    }

    // 5) attention (bf16 out): one block per strip per (b,h)
    attn_mfma<<<128 * Hsz * Bsz, 256, 0, stream>>>(qkvb, vt, sel,
                                                   local_w, global_w, attnb);

    // 6) output projection (fp32 out, no scaling)
    {
        dim3 g(Csz / 128, M / 128);
        gemm_bt_mfma<0><<<g, 256, 0, stream>>>(attnb, wp, c_proj_b, out,
                                               M, Csz, Csz, 0);
    }
}